// Round 10
// baseline (434.436 us; speedup 1.0000x reference)
//
#include <hip/hip_runtime.h>

#define NN 50000
#define D 128
#define EE 600000
#define R 8
#define NR (NN * R)            /* segments, key = dst*R + rel (node-major) */
#define SCAN_CHUNK 1024
#define NSB ((NR + SCAN_CHUNK - 1) / SCAN_CHUNK) /* 391 */
#define KO 1152                /* output cols of gemm_xw: 8*128 + 128 */

typedef unsigned short u16;
typedef unsigned int u32;
typedef __attribute__((ext_vector_type(8))) short bf16x8;
typedef __attribute__((ext_vector_type(4))) float f32x4;

__device__ inline u16 f2bf(float f) {
    union { float f; u32 u; } v; v.f = f;
    return (u16)((v.u + 0x7FFFu + ((v.u >> 16) & 1u)) >> 16);
}
__device__ inline float bf2f(u16 h) {
    union { u32 u; float f; } v; v.u = ((u32)h) << 16;
    return v.f;
}

// ---- cast x fp32 -> packed bf16 pairs ----
__global__ __launch_bounds__(256) void xcast_kernel(const float2* __restrict__ x2,
                                                    u32* __restrict__ xb, int n) {
    int i = blockIdx.x * 256 + threadIdx.x;
    if (i < n) {
        float2 v = x2[i];
        xb[i] = (u32)f2bf(v.x) | ((u32)f2bf(v.y) << 16);
    }
}

// ---- histogram per segment key = dst*R + rel ----
__global__ __launch_bounds__(256) void hist_kernel(const int* __restrict__ dst,
                                                   const int* __restrict__ et,
                                                   int* __restrict__ cnt, int E) {
    int e = blockIdx.x * 256 + threadIdx.x;
    if (e < E) atomicAdd(&cnt[dst[e] * R + et[e]], 1);
}

// ---- exclusive scan, 3-pass ----
__global__ __launch_bounds__(256) void scanA(const int* __restrict__ cnt,
                                             int* __restrict__ off,
                                             int* __restrict__ bsum) {
    __shared__ int ts[256];
    const int b = blockIdx.x, t = threadIdx.x;
    const int base = b * SCAN_CHUNK + t * 4;
    int v0 = 0, v1 = 0, v2 = 0, v3 = 0;
    if (base + 3 < NR) {
        int4 q = *(const int4*)(cnt + base);
        v0 = q.x; v1 = q.y; v2 = q.z; v3 = q.w;
    } else {
        if (base < NR) v0 = cnt[base];
        if (base + 1 < NR) v1 = cnt[base + 1];
        if (base + 2 < NR) v2 = cnt[base + 2];
    }
    const int s = v0 + v1 + v2 + v3;
    ts[t] = s;
    __syncthreads();
    for (int d = 1; d < 256; d <<= 1) {
        int x = (t >= d) ? ts[t - d] : 0;
        __syncthreads();
        ts[t] += x;
        __syncthreads();
    }
    const int excl = ts[t] - s;
    if (base < NR) off[base] = excl;
    if (base + 1 < NR) off[base + 1] = excl + v0;
    if (base + 2 < NR) off[base + 2] = excl + v0 + v1;
    if (base + 3 < NR) off[base + 3] = excl + v0 + v1 + v2;
    if (t == 255) bsum[b] = ts[255];
}

__global__ __launch_bounds__(512) void scanB(const int* __restrict__ bsum,
                                             int* __restrict__ boff) {
    __shared__ int ts[512];
    const int t = threadIdx.x;
    const int v = (t < NSB) ? bsum[t] : 0;
    ts[t] = v;
    __syncthreads();
    for (int d = 1; d < 512; d <<= 1) {
        int x = (t >= d) ? ts[t - d] : 0;
        __syncthreads();
        ts[t] += x;
        __syncthreads();
    }
    if (t < NSB) boff[t] = ts[t] - v;
}

// adds block offsets; writes BOTH off and cursor (saves a d2d copy)
__global__ __launch_bounds__(256) void scanC(int* __restrict__ off,
                                             int* __restrict__ cursor,
                                             const int* __restrict__ boff) {
    const int b = blockIdx.x, t = threadIdx.x;
    const int add = boff[b];
    const int base = b * SCAN_CHUNK + t * 4;
#pragma unroll
    for (int j = 0; j < 4; ++j)
        if (base + j < NR) {
            int v = off[base + j] + add;
            off[base + j] = v;
            cursor[base + j] = v;
        }
    if (b == 0 && t == 0) off[NR] = EE;
}

// ---- place: ONE packed uint2 store per edge (offset in u32-units, scale) ----
// Single 8 B store dirties one cache line per edge (round-9: two 4 B stores
// dirtied two lines -> 64 MB write-amp; this halves it).
__global__ __launch_bounds__(256) void place_kernel(const int* __restrict__ src,
                                                    const int* __restrict__ dst,
                                                    const int* __restrict__ et,
                                                    const int* __restrict__ cnt,
                                                    int* __restrict__ cursor,
                                                    uint2* __restrict__ edat, int E) {
    int e = blockIdx.x * 256 + threadIdx.x;
    if (e < E) {
        int r = et[e];
        int key = dst[e] * R + r;
        int p = atomicAdd(&cursor[key], 1);
        float s = 1.0f / (float)cnt[key];
        edat[p] = make_uint2((u32)src[e] * (KO / 2) + (u32)r * (D / 2),
                             __float_as_uint(s));
    }
}

// ---- pack both layers' B = [W_1..W_8, root] (cols) into MFMA B-frag order ----
// layout: [layer][ct(9)][kc(4)][g(8)][lane(64)][j(8)]
// value = B[k = kc*32 + quad*8 + j][col = ct*128 + g*16 + l15]
__global__ __launch_bounds__(256) void bprep2_kernel(const float* __restrict__ w1,
                                                     const float* __restrict__ root1,
                                                     u16* __restrict__ Bf1,
                                                     const float* __restrict__ w2,
                                                     const float* __restrict__ root2,
                                                     u16* __restrict__ Bf2) {
    int gidx = blockIdx.x * 256 + threadIdx.x;  // over 2*9*4*8*64 = 36864
    if (gidx >= 2 * 9 * 4 * 8 * 64) return;
    const int layer = gidx / (9 * 4 * 8 * 64);
    const int idx = gidx - layer * (9 * 4 * 8 * 64);
    const float* w = layer ? w2 : w1;
    const float* root = layer ? root2 : root1;
    u16* Bfrag = layer ? Bf2 : Bf1;
    const int lane = idx & 63;
    const int g = (idx >> 6) & 7;
    const int kc = (idx >> 9) & 3;
    const int ct = idx >> 11;  // 0..8
    const int col = ct * 128 + g * 16 + (lane & 15);
    const int kbase = kc * 32 + (lane >> 4) * 8;
    u16* o = Bfrag + (size_t)idx * 8;
#pragma unroll
    for (int j = 0; j < 8; ++j) {
        const int k = kbase + j;
        float v = (col < R * D) ? w[(size_t)(col >> 7) * (D * D) + (size_t)k * D + (col & 127)]
                                : root[(size_t)k * D + (col - R * D)];
        o[j] = f2bf(v);
    }
}

// ---- GEMM: y[n,:] = xin[n,:] @ [W_1..W_8, root]  (K=128, bf16 out) ----
// grid 782; ct-loop INSIDE the block so xin is read once (round-9 read it
// 9x: FETCH 57 MB). Per ct, the 32 KB B slice is staged in LDS (2-barrier).
__global__ __launch_bounds__(256) void gemm_xw(const u16* __restrict__ xin,
                                               const u16* __restrict__ Bfrag,
                                               u16* __restrict__ y) {
    __shared__ uint4 Bs[2048];  // 32 KB

    const int t = threadIdx.x;
    const int wave = t >> 6;
    const int lane = t & 63;
    const int quad = lane >> 4;
    const int l15 = lane & 15;
    const int n0 = blockIdx.x * 64;
    const int n = n0 + wave * 16 + l15;
    const int nc = (n < NN) ? n : (NN - 1);

    // A fragments (K = 128 -> 4 chunks), loaded once
    const u16* xr = xin + (size_t)nc * D + quad * 8;
    bf16x8 a0 = *(const bf16x8*)(xr);
    bf16x8 a1 = *(const bf16x8*)(xr + 32);
    bf16x8 a2 = *(const bf16x8*)(xr + 64);
    bf16x8 a3 = *(const bf16x8*)(xr + 96);

#pragma unroll 1
    for (int ct = 0; ct < 9; ++ct) {
        // issue this tile's B loads (in flight across the first barrier)
        const uint4* bsrc = (const uint4*)Bfrag + (size_t)ct * 2048;
        uint4 s[8];
#pragma unroll
        for (int i = 0; i < 8; ++i) s[i] = bsrc[t + 256 * i];

        __syncthreads();  // previous tile's LDS reads complete
#pragma unroll
        for (int i = 0; i < 8; ++i) Bs[t + 256 * i] = s[i];
        __syncthreads();  // stage visible

        f32x4 acc[8];
#pragma unroll
        for (int g = 0; g < 8; ++g) acc[g] = (f32x4){0.f, 0.f, 0.f, 0.f};

        const u16* bb = (const u16*)Bs + lane * 8;
#pragma unroll
        for (int g = 0; g < 8; ++g) {
            bf16x8 b0 = *(const bf16x8*)(bb + (0 * 8 + g) * 512);
            acc[g] = __builtin_amdgcn_mfma_f32_16x16x32_bf16(a0, b0, acc[g], 0, 0, 0);
            bf16x8 b1 = *(const bf16x8*)(bb + (1 * 8 + g) * 512);
            acc[g] = __builtin_amdgcn_mfma_f32_16x16x32_bf16(a1, b1, acc[g], 0, 0, 0);
            bf16x8 b2 = *(const bf16x8*)(bb + (2 * 8 + g) * 512);
            acc[g] = __builtin_amdgcn_mfma_f32_16x16x32_bf16(a2, b2, acc[g], 0, 0, 0);
            bf16x8 b3 = *(const bf16x8*)(bb + (3 * 8 + g) * 512);
            acc[g] = __builtin_amdgcn_mfma_f32_16x16x32_bf16(a3, b3, acc[g], 0, 0, 0);
        }

        // epilogue: D mapping row = quad*4 + q, col = g*16 + l15
#pragma unroll
        for (int g = 0; g < 8; ++g) {
            const int col = ct * 128 + g * 16 + l15;
#pragma unroll
            for (int q = 0; q < 4; ++q) {
                const int row = n0 + wave * 16 + quad * 4 + q;
                if (row < NN)
                    y[(size_t)row * KO + col] = f2bf(acc[g][q]);
            }
        }
    }
}

// ---- aggregate: out[n] = relu( sum_e scale*y[src_e, r_e*128..] + y[n,1024..] + b )
// One wave per node; packed per-edge (offset, scale) broadcast via shfl;
// 4-wide batched gathers for MLP.
template <bool OUTBF>
__global__ __launch_bounds__(256) void agg_kernel(const u32* __restrict__ yv,
                                                  const int* __restrict__ off,
                                                  const uint2* __restrict__ edat,
                                                  const float* __restrict__ bias,
                                                  void* __restrict__ outp) {
    const int n = blockIdx.x * 4 + (threadIdx.x >> 6);
    const int lane = threadIdx.x & 63;
    const int e0 = off[n * 8], e1 = off[n * 8 + 8];

    float ax = 0.f, ay = 0.f;
    int cbase = e0;
    uint2 ev = make_uint2(0u, 0u);
    if (cbase + lane < e1) ev = edat[cbase + lane];

    int i = e0;
    while (i < e1) {
        const int chunk_end = (e1 < cbase + 64) ? e1 : (cbase + 64);
        for (; i + 3 < chunk_end; i += 4) {
            const int j = i - cbase;
            const u32 p0 = (u32)__shfl((int)ev.x, j);
            const u32 p1 = (u32)__shfl((int)ev.x, j + 1);
            const u32 p2 = (u32)__shfl((int)ev.x, j + 2);
            const u32 p3 = (u32)__shfl((int)ev.x, j + 3);
            const float f0 = __uint_as_float((u32)__shfl((int)ev.y, j));
            const float f1 = __uint_as_float((u32)__shfl((int)ev.y, j + 1));
            const float f2 = __uint_as_float((u32)__shfl((int)ev.y, j + 2));
            const float f3 = __uint_as_float((u32)__shfl((int)ev.y, j + 3));
            const u32 v0 = yv[(size_t)p0 + lane];
            const u32 v1 = yv[(size_t)p1 + lane];
            const u32 v2 = yv[(size_t)p2 + lane];
            const u32 v3 = yv[(size_t)p3 + lane];
            ax += f0 * bf2f((u16)(v0 & 0xFFFFu)); ay += f0 * bf2f((u16)(v0 >> 16));
            ax += f1 * bf2f((u16)(v1 & 0xFFFFu)); ay += f1 * bf2f((u16)(v1 >> 16));
            ax += f2 * bf2f((u16)(v2 & 0xFFFFu)); ay += f2 * bf2f((u16)(v2 >> 16));
            ax += f3 * bf2f((u16)(v3 & 0xFFFFu)); ay += f3 * bf2f((u16)(v3 >> 16));
        }
        for (; i < chunk_end; ++i) {
            const int j = i - cbase;
            const u32 p0 = (u32)__shfl((int)ev.x, j);
            const float f0 = __uint_as_float((u32)__shfl((int)ev.y, j));
            const u32 v0 = yv[(size_t)p0 + lane];
            ax += f0 * bf2f((u16)(v0 & 0xFFFFu));
            ay += f0 * bf2f((u16)(v0 >> 16));
        }
        if (i < e1) {  // next chunk of 64 edges (rare)
            cbase += 64;
            ev = (cbase + lane < e1) ? edat[cbase + lane] : make_uint2(0u, 0u);
        }
    }

    // root term + bias + relu
    const u32 rv = yv[(size_t)n * (KO / 2) + (R * D / 2) + lane];
    const float2 bb = ((const float2*)bias)[lane];
    const float ox = fmaxf(ax + bf2f((u16)(rv & 0xFFFFu)) + bb.x, 0.f);
    const float oy = fmaxf(ay + bf2f((u16)(rv >> 16)) + bb.y, 0.f);
    if (OUTBF)
        ((u32*)outp)[(size_t)n * 64 + lane] = (u32)f2bf(ox) | ((u32)f2bf(oy) << 16);
    else
        ((float2*)outp)[(size_t)n * 64 + lane] = make_float2(ox, oy);
}

extern "C" void kernel_launch(void* const* d_in, const int* in_sizes, int n_in,
                              void* d_out, int out_size, void* d_ws, size_t ws_size,
                              hipStream_t stream) {
    const float* x = (const float*)d_in[0];
    const int* ei = (const int*)d_in[1];
    const int* et = (const int*)d_in[2];
    const float* w1 = (const float*)d_in[3];
    const float* root1 = (const float*)d_in[4];
    const float* b1 = (const float*)d_in[5];
    const float* w2 = (const float*)d_in[6];
    const float* root2 = (const float*)d_in[7];
    const float* b2 = (const float*)d_in[8];
    float* out = (float*)d_out;

    char* ws = (char*)d_ws;
    int* off    = (int*)(ws + 0);                  // (NR+1) ints
    int* cnt_i  = (int*)(ws + 1600512);            // NR ints
    int* cursor = (int*)(ws + 3200512);            // NR ints
    int* bsum   = (int*)(ws + 4800512);
    int* boff   = (int*)(ws + 4802304);
    uint2* edat = (uint2*)(ws + 4804096);          // EE uint2 (4.8 MB)
    u32* xb     = (u32*)(ws + 9604096);            // N*D bf16 = 12.8 MB
    u32* h      = (u32*)(ws + 22404096);           // N*D bf16 = 12.8 MB
    u16* y      = (u16*)(ws + 35204096);           // N*1152 bf16 = 115.2 MB
    u16* Bf1    = (u16*)(ws + 150404096);          // 294912 B
    u16* Bf2    = (u16*)(ws + 150699008);          // 294912 B

    const int* srcp = ei;
    const int* dstp = ei + EE;

    // ---- input cast + CSR build (shared by both layers) ----
    xcast_kernel<<<(NN * D / 2 + 255) / 256, 256, 0, stream>>>((const float2*)x,
                                                               xb, NN * D / 2);
    hipMemsetAsync(cnt_i, 0, (size_t)NR * sizeof(int), stream);
    hist_kernel<<<(EE + 255) / 256, 256, 0, stream>>>(dstp, et, cnt_i, EE);
    scanA<<<NSB, 256, 0, stream>>>(cnt_i, off, bsum);
    scanB<<<1, 512, 0, stream>>>(bsum, boff);
    scanC<<<NSB, 256, 0, stream>>>(off, cursor, boff);
    place_kernel<<<(EE + 255) / 256, 256, 0, stream>>>(srcp, dstp, et, cnt_i,
                                                       cursor, edat, EE);
    bprep2_kernel<<<(2 * 9 * 4 * 8 * 64 + 255) / 256, 256, 0, stream>>>(
        w1, root1, Bf1, w2, root2, Bf2);

    const int gemm_blocks = (NN + 63) / 64;   // 782
    const int agg_blocks = NN / 4;            // 12500

    // layer 1: xb -> y -> h (bf16)
    gemm_xw<<<gemm_blocks, 256, 0, stream>>>((const u16*)xb, Bf1, y);
    agg_kernel<true><<<agg_blocks, 256, 0, stream>>>((const u32*)y, off, edat,
                                                     b1, h);

    // layer 2: h -> y -> out (fp32)
    gemm_xw<<<gemm_blocks, 256, 0, stream>>>((const u16*)h, Bf2, y);
    agg_kernel<false><<<agg_blocks, 256, 0, stream>>>((const u32*)y, off, edat,
                                                      b2, out);
}

// Round 11
// 294.067 us; speedup vs baseline: 1.4773x; 1.4773x over previous
//
#include <hip/hip_runtime.h>

#define NN 50000
#define D 128
#define EE 600000
#define R 8
#define NR (NN * R)            /* segments, key = dst*R + rel (node-major) */
#define SCAN_CHUNK 1024
#define NSB ((NR + SCAN_CHUNK - 1) / SCAN_CHUNK) /* 391 */
#define KO 1152                /* output cols of gemm_xw: 8*128 + 128 */

typedef unsigned short u16;
typedef unsigned int u32;
typedef __attribute__((ext_vector_type(8))) short bf16x8;
typedef __attribute__((ext_vector_type(4))) float f32x4;

__device__ inline u16 f2bf(float f) {
    union { float f; u32 u; } v; v.f = f;
    return (u16)((v.u + 0x7FFFu + ((v.u >> 16) & 1u)) >> 16);
}
__device__ inline float bf2f(u16 h) {
    union { u32 u; float f; } v; v.u = ((u32)h) << 16;
    return v.f;
}

// ---- cast x fp32 -> packed bf16 pairs ----
__global__ __launch_bounds__(256) void xcast_kernel(const float2* __restrict__ x2,
                                                    u32* __restrict__ xb, int n) {
    int i = blockIdx.x * 256 + threadIdx.x;
    if (i < n) {
        float2 v = x2[i];
        xb[i] = (u32)f2bf(v.x) | ((u32)f2bf(v.y) << 16);
    }
}

// ---- histogram per segment key = dst*R + rel ----
__global__ __launch_bounds__(256) void hist_kernel(const int* __restrict__ dst,
                                                   const int* __restrict__ et,
                                                   int* __restrict__ cnt, int E) {
    int e = blockIdx.x * 256 + threadIdx.x;
    if (e < E) atomicAdd(&cnt[dst[e] * R + et[e]], 1);
}

// ---- exclusive scan, 3-pass ----
__global__ __launch_bounds__(256) void scanA(const int* __restrict__ cnt,
                                             int* __restrict__ off,
                                             int* __restrict__ bsum) {
    __shared__ int ts[256];
    const int b = blockIdx.x, t = threadIdx.x;
    const int base = b * SCAN_CHUNK + t * 4;
    int v0 = 0, v1 = 0, v2 = 0, v3 = 0;
    if (base + 3 < NR) {
        int4 q = *(const int4*)(cnt + base);
        v0 = q.x; v1 = q.y; v2 = q.z; v3 = q.w;
    } else {
        if (base < NR) v0 = cnt[base];
        if (base + 1 < NR) v1 = cnt[base + 1];
        if (base + 2 < NR) v2 = cnt[base + 2];
    }
    const int s = v0 + v1 + v2 + v3;
    ts[t] = s;
    __syncthreads();
    for (int d = 1; d < 256; d <<= 1) {
        int x = (t >= d) ? ts[t - d] : 0;
        __syncthreads();
        ts[t] += x;
        __syncthreads();
    }
    const int excl = ts[t] - s;
    if (base < NR) off[base] = excl;
    if (base + 1 < NR) off[base + 1] = excl + v0;
    if (base + 2 < NR) off[base + 2] = excl + v0 + v1;
    if (base + 3 < NR) off[base + 3] = excl + v0 + v1 + v2;
    if (t == 255) bsum[b] = ts[255];
}

__global__ __launch_bounds__(512) void scanB(const int* __restrict__ bsum,
                                             int* __restrict__ boff) {
    __shared__ int ts[512];
    const int t = threadIdx.x;
    const int v = (t < NSB) ? bsum[t] : 0;
    ts[t] = v;
    __syncthreads();
    for (int d = 1; d < 512; d <<= 1) {
        int x = (t >= d) ? ts[t - d] : 0;
        __syncthreads();
        ts[t] += x;
        __syncthreads();
    }
    if (t < NSB) boff[t] = ts[t] - v;
}

// adds block offsets; writes BOTH off and cursor (saves a d2d copy)
__global__ __launch_bounds__(256) void scanC(int* __restrict__ off,
                                             int* __restrict__ cursor,
                                             const int* __restrict__ boff) {
    const int b = blockIdx.x, t = threadIdx.x;
    const int add = boff[b];
    const int base = b * SCAN_CHUNK + t * 4;
#pragma unroll
    for (int j = 0; j < 4; ++j)
        if (base + j < NR) {
            int v = off[base + j] + add;
            off[base + j] = v;
            cursor[base + j] = v;
        }
    if (b == 0 && t == 0) off[NR] = EE;
}

// ---- place: ONE packed uint2 store per edge (offset in u32-units, scale) ----
__global__ __launch_bounds__(256) void place_kernel(const int* __restrict__ src,
                                                    const int* __restrict__ dst,
                                                    const int* __restrict__ et,
                                                    const int* __restrict__ cnt,
                                                    int* __restrict__ cursor,
                                                    uint2* __restrict__ edat, int E) {
    int e = blockIdx.x * 256 + threadIdx.x;
    if (e < E) {
        int r = et[e];
        int key = dst[e] * R + r;
        int p = atomicAdd(&cursor[key], 1);
        float s = 1.0f / (float)cnt[key];
        edat[p] = make_uint2((u32)src[e] * (KO / 2) + (u32)r * (D / 2),
                             __float_as_uint(s));
    }
}

// ---- pack both layers' B = [W_1..W_8, root] (cols) into MFMA B-frag order ----
// layout: [layer][ct(9)][kc(4)][g(8)][lane(64)][j(8)]
// value = B[k = kc*32 + quad*8 + j][col = ct*128 + g*16 + l15]
__global__ __launch_bounds__(256) void bprep2_kernel(const float* __restrict__ w1,
                                                     const float* __restrict__ root1,
                                                     u16* __restrict__ Bf1,
                                                     const float* __restrict__ w2,
                                                     const float* __restrict__ root2,
                                                     u16* __restrict__ Bf2) {
    int gidx = blockIdx.x * 256 + threadIdx.x;  // over 2*9*4*8*64 = 36864
    if (gidx >= 2 * 9 * 4 * 8 * 64) return;
    const int layer = gidx / (9 * 4 * 8 * 64);
    const int idx = gidx - layer * (9 * 4 * 8 * 64);
    const float* w = layer ? w2 : w1;
    const float* root = layer ? root2 : root1;
    u16* Bfrag = layer ? Bf2 : Bf1;
    const int lane = idx & 63;
    const int g = (idx >> 6) & 7;
    const int kc = (idx >> 9) & 3;
    const int ct = idx >> 11;  // 0..8
    const int col = ct * 128 + g * 16 + (lane & 15);
    const int kbase = kc * 32 + (lane >> 4) * 8;
    u16* o = Bfrag + (size_t)idx * 8;
#pragma unroll
    for (int j = 0; j < 8; ++j) {
        const int k = kbase + j;
        float v = (col < R * D) ? w[(size_t)(col >> 7) * (D * D) + (size_t)k * D + (col & 127)]
                                : root[(size_t)k * D + (col - R * D)];
        o[j] = f2bf(v);
    }
}

// ---- GEMM: y[n,:] = xin[n,:] @ [W_1..W_8, root]  (K=128, bf16 out) ----
// grid 782; ct-loop inside so xin is read once. B slice (32 KB) staged per ct
// with immediate load->ds_write INSIDE the barrier pair — NO values held in
// registers across a barrier (round-10's register-carried stage spilled to
// scratch: +225 MB HBM writes). __launch_bounds__(256,4): VGPR cap 128.
__global__ __launch_bounds__(256, 4) void gemm_xw(const u16* __restrict__ xin,
                                                  const u16* __restrict__ Bfrag,
                                                  u16* __restrict__ y) {
    __shared__ uint4 Bs[2048];  // 32 KB

    const int t = threadIdx.x;
    const int wave = t >> 6;
    const int lane = t & 63;
    const int quad = lane >> 4;
    const int l15 = lane & 15;
    const int n0 = blockIdx.x * 64;
    const int n = n0 + wave * 16 + l15;
    const int nc = (n < NN) ? n : (NN - 1);

    // A fragments (K = 128 -> 4 chunks), loaded once
    const u16* xr = xin + (size_t)nc * D + quad * 8;
    bf16x8 a0 = *(const bf16x8*)(xr);
    bf16x8 a1 = *(const bf16x8*)(xr + 32);
    bf16x8 a2 = *(const bf16x8*)(xr + 64);
    bf16x8 a3 = *(const bf16x8*)(xr + 96);

#pragma unroll 1
    for (int ct = 0; ct < 9; ++ct) {
        const uint4* bsrc = (const uint4*)Bfrag + (size_t)ct * 2048 + t;

        __syncthreads();  // previous tile's LDS reads complete
#pragma unroll
        for (int i = 0; i < 8; ++i) Bs[t + 256 * i] = bsrc[256 * i];
        __syncthreads();  // stage visible

        f32x4 acc[8];
#pragma unroll
        for (int g = 0; g < 8; ++g) acc[g] = (f32x4){0.f, 0.f, 0.f, 0.f};

        const u16* bb = (const u16*)Bs + lane * 8;
#pragma unroll
        for (int g = 0; g < 8; ++g) {
            bf16x8 b0 = *(const bf16x8*)(bb + (0 * 8 + g) * 512);
            acc[g] = __builtin_amdgcn_mfma_f32_16x16x32_bf16(a0, b0, acc[g], 0, 0, 0);
            bf16x8 b1 = *(const bf16x8*)(bb + (1 * 8 + g) * 512);
            acc[g] = __builtin_amdgcn_mfma_f32_16x16x32_bf16(a1, b1, acc[g], 0, 0, 0);
            bf16x8 b2 = *(const bf16x8*)(bb + (2 * 8 + g) * 512);
            acc[g] = __builtin_amdgcn_mfma_f32_16x16x32_bf16(a2, b2, acc[g], 0, 0, 0);
            bf16x8 b3 = *(const bf16x8*)(bb + (3 * 8 + g) * 512);
            acc[g] = __builtin_amdgcn_mfma_f32_16x16x32_bf16(a3, b3, acc[g], 0, 0, 0);
        }

        // epilogue: D mapping row = quad*4 + q, col = g*16 + l15
#pragma unroll
        for (int g = 0; g < 8; ++g) {
            const int col = ct * 128 + g * 16 + l15;
#pragma unroll
            for (int q = 0; q < 4; ++q) {
                const int row = n0 + wave * 16 + quad * 4 + q;
                if (row < NN)
                    y[(size_t)row * KO + col] = f2bf(acc[g][q]);
            }
        }
    }
}

// ---- aggregate: out[n] = relu( sum_e scale*y[src_e, r_e*128..] + y[n,1024..] + b )
// One wave per node; packed per-edge (offset, scale) broadcast via shfl;
// 4-wide batched gathers for MLP.
template <bool OUTBF>
__global__ __launch_bounds__(256) void agg_kernel(const u32* __restrict__ yv,
                                                  const int* __restrict__ off,
                                                  const uint2* __restrict__ edat,
                                                  const float* __restrict__ bias,
                                                  void* __restrict__ outp) {
    const int n = blockIdx.x * 4 + (threadIdx.x >> 6);
    const int lane = threadIdx.x & 63;
    const int e0 = off[n * 8], e1 = off[n * 8 + 8];

    float ax = 0.f, ay = 0.f;
    int cbase = e0;
    uint2 ev = make_uint2(0u, 0u);
    if (cbase + lane < e1) ev = edat[cbase + lane];

    int i = e0;
    while (i < e1) {
        const int chunk_end = (e1 < cbase + 64) ? e1 : (cbase + 64);
        for (; i + 3 < chunk_end; i += 4) {
            const int j = i - cbase;
            const u32 p0 = (u32)__shfl((int)ev.x, j);
            const u32 p1 = (u32)__shfl((int)ev.x, j + 1);
            const u32 p2 = (u32)__shfl((int)ev.x, j + 2);
            const u32 p3 = (u32)__shfl((int)ev.x, j + 3);
            const float f0 = __uint_as_float((u32)__shfl((int)ev.y, j));
            const float f1 = __uint_as_float((u32)__shfl((int)ev.y, j + 1));
            const float f2 = __uint_as_float((u32)__shfl((int)ev.y, j + 2));
            const float f3 = __uint_as_float((u32)__shfl((int)ev.y, j + 3));
            const u32 v0 = yv[(size_t)p0 + lane];
            const u32 v1 = yv[(size_t)p1 + lane];
            const u32 v2 = yv[(size_t)p2 + lane];
            const u32 v3 = yv[(size_t)p3 + lane];
            ax += f0 * bf2f((u16)(v0 & 0xFFFFu)); ay += f0 * bf2f((u16)(v0 >> 16));
            ax += f1 * bf2f((u16)(v1 & 0xFFFFu)); ay += f1 * bf2f((u16)(v1 >> 16));
            ax += f2 * bf2f((u16)(v2 & 0xFFFFu)); ay += f2 * bf2f((u16)(v2 >> 16));
            ax += f3 * bf2f((u16)(v3 & 0xFFFFu)); ay += f3 * bf2f((u16)(v3 >> 16));
        }
        for (; i < chunk_end; ++i) {
            const int j = i - cbase;
            const u32 p0 = (u32)__shfl((int)ev.x, j);
            const float f0 = __uint_as_float((u32)__shfl((int)ev.y, j));
            const u32 v0 = yv[(size_t)p0 + lane];
            ax += f0 * bf2f((u16)(v0 & 0xFFFFu));
            ay += f0 * bf2f((u16)(v0 >> 16));
        }
        if (i < e1) {  // next chunk of 64 edges (rare)
            cbase += 64;
            ev = (cbase + lane < e1) ? edat[cbase + lane] : make_uint2(0u, 0u);
        }
    }

    // root term + bias + relu
    const u32 rv = yv[(size_t)n * (KO / 2) + (R * D / 2) + lane];
    const float2 bb = ((const float2*)bias)[lane];
    const float ox = fmaxf(ax + bf2f((u16)(rv & 0xFFFFu)) + bb.x, 0.f);
    const float oy = fmaxf(ay + bf2f((u16)(rv >> 16)) + bb.y, 0.f);
    if (OUTBF)
        ((u32*)outp)[(size_t)n * 64 + lane] = (u32)f2bf(ox) | ((u32)f2bf(oy) << 16);
    else
        ((float2*)outp)[(size_t)n * 64 + lane] = make_float2(ox, oy);
}

extern "C" void kernel_launch(void* const* d_in, const int* in_sizes, int n_in,
                              void* d_out, int out_size, void* d_ws, size_t ws_size,
                              hipStream_t stream) {
    const float* x = (const float*)d_in[0];
    const int* ei = (const int*)d_in[1];
    const int* et = (const int*)d_in[2];
    const float* w1 = (const float*)d_in[3];
    const float* root1 = (const float*)d_in[4];
    const float* b1 = (const float*)d_in[5];
    const float* w2 = (const float*)d_in[6];
    const float* root2 = (const float*)d_in[7];
    const float* b2 = (const float*)d_in[8];
    float* out = (float*)d_out;

    char* ws = (char*)d_ws;
    int* off    = (int*)(ws + 0);                  // (NR+1) ints
    int* cnt_i  = (int*)(ws + 1600512);            // NR ints
    int* cursor = (int*)(ws + 3200512);            // NR ints
    int* bsum   = (int*)(ws + 4800512);
    int* boff   = (int*)(ws + 4802304);
    uint2* edat = (uint2*)(ws + 4804096);          // EE uint2 (4.8 MB)
    u32* xb     = (u32*)(ws + 9604096);            // N*D bf16 = 12.8 MB
    u32* h      = (u32*)(ws + 22404096);           // N*D bf16 = 12.8 MB
    u16* y      = (u16*)(ws + 35204096);           // N*1152 bf16 = 115.2 MB
    u16* Bf1    = (u16*)(ws + 150404096);          // 294912 B
    u16* Bf2    = (u16*)(ws + 150699008);          // 294912 B

    const int* srcp = ei;
    const int* dstp = ei + EE;

    // ---- input cast + CSR build (shared by both layers) ----
    xcast_kernel<<<(NN * D / 2 + 255) / 256, 256, 0, stream>>>((const float2*)x,
                                                               xb, NN * D / 2);
    hipMemsetAsync(cnt_i, 0, (size_t)NR * sizeof(int), stream);
    hist_kernel<<<(EE + 255) / 256, 256, 0, stream>>>(dstp, et, cnt_i, EE);
    scanA<<<NSB, 256, 0, stream>>>(cnt_i, off, bsum);
    scanB<<<1, 512, 0, stream>>>(bsum, boff);
    scanC<<<NSB, 256, 0, stream>>>(off, cursor, boff);
    place_kernel<<<(EE + 255) / 256, 256, 0, stream>>>(srcp, dstp, et, cnt_i,
                                                       cursor, edat, EE);
    bprep2_kernel<<<(2 * 9 * 4 * 8 * 64 + 255) / 256, 256, 0, stream>>>(
        w1, root1, Bf1, w2, root2, Bf2);

    const int gemm_blocks = (NN + 63) / 64;   // 782
    const int agg_blocks = NN / 4;            // 12500

    // layer 1: xb -> y -> h (bf16)
    gemm_xw<<<gemm_blocks, 256, 0, stream>>>((const u16*)xb, Bf1, y);
    agg_kernel<true><<<agg_blocks, 256, 0, stream>>>((const u32*)y, off, edat,
                                                     b1, h);

    // layer 2: h -> y -> out (fp32)
    gemm_xw<<<gemm_blocks, 256, 0, stream>>>((const u16*)h, Bf2, y);
    agg_kernel<false><<<agg_blocks, 256, 0, stream>>>((const u32*)y, off, edat,
                                                      b2, out);
}

// Round 12
// 284.171 us; speedup vs baseline: 1.5288x; 1.0348x over previous
//
#include <hip/hip_runtime.h>

#define NN 50000
#define D 128
#define EE 600000
#define R 8
#define NR (NN * R)            /* segments, key = dst*R + rel (node-major) */
#define SCAN_CHUNK 1024
#define NSB ((NR + SCAN_CHUNK - 1) / SCAN_CHUNK) /* 391 */
#define KO 1152                /* output cols of gemm_xw: 8*128 + 128 */

typedef unsigned short u16;
typedef unsigned int u32;
typedef __attribute__((ext_vector_type(8))) short bf16x8;
typedef __attribute__((ext_vector_type(4))) float f32x4;

__device__ inline u16 f2bf(float f) {
    union { float f; u32 u; } v; v.f = f;
    return (u16)((v.u + 0x7FFFu + ((v.u >> 16) & 1u)) >> 16);
}
__device__ inline float bf2f(u16 h) {
    union { u32 u; float f; } v; v.u = ((u32)h) << 16;
    return v.f;
}

// ---- histogram per segment key = dst*R + rel ----
__global__ __launch_bounds__(256) void hist_kernel(const int* __restrict__ dst,
                                                   const int* __restrict__ et,
                                                   int* __restrict__ cnt, int E) {
    int e = blockIdx.x * 256 + threadIdx.x;
    if (e < E) atomicAdd(&cnt[dst[e] * R + et[e]], 1);
}

// ---- exclusive scan pass A ----
__global__ __launch_bounds__(256) void scanA(const int* __restrict__ cnt,
                                             int* __restrict__ off,
                                             int* __restrict__ bsum) {
    __shared__ int ts[256];
    const int b = blockIdx.x, t = threadIdx.x;
    const int base = b * SCAN_CHUNK + t * 4;
    int v0 = 0, v1 = 0, v2 = 0, v3 = 0;
    if (base + 3 < NR) {
        int4 q = *(const int4*)(cnt + base);
        v0 = q.x; v1 = q.y; v2 = q.z; v3 = q.w;
    } else {
        if (base < NR) v0 = cnt[base];
        if (base + 1 < NR) v1 = cnt[base + 1];
        if (base + 2 < NR) v2 = cnt[base + 2];
    }
    const int s = v0 + v1 + v2 + v3;
    ts[t] = s;
    __syncthreads();
    for (int d = 1; d < 256; d <<= 1) {
        int x = (t >= d) ? ts[t - d] : 0;
        __syncthreads();
        ts[t] += x;
        __syncthreads();
    }
    const int excl = ts[t] - s;
    if (base < NR) off[base] = excl;
    if (base + 1 < NR) off[base + 1] = excl + v0;
    if (base + 2 < NR) off[base + 2] = excl + v0 + v1;
    if (base + 3 < NR) off[base + 3] = excl + v0 + v1 + v2;
    if (t == 255) bsum[b] = ts[255];
}

// ---- scan pass B+C fused: each block reduces its own bsum prefix, then
// adds it to its off chunk and mirrors into cursor (saves a dispatch + d2d).
__global__ __launch_bounds__(256) void scanBC(int* __restrict__ off,
                                              int* __restrict__ cursor,
                                              const int* __restrict__ bsum) {
    __shared__ int red[256];
    const int b = blockIdx.x, t = threadIdx.x;
    int p = 0;
    for (int i = t; i < b; i += 256) p += bsum[i];
    red[t] = p;
    __syncthreads();
    for (int d = 128; d > 0; d >>= 1) {
        if (t < d) red[t] += red[t + d];
        __syncthreads();
    }
    const int add = red[0];
    const int base = b * SCAN_CHUNK + t * 4;
#pragma unroll
    for (int j = 0; j < 4; ++j)
        if (base + j < NR) {
            int v = off[base + j] + add;
            off[base + j] = v;
            cursor[base + j] = v;
        }
    if (b == 0 && t == 0) off[NR] = EE;
}

// ---- place: ONE packed u32 store per edge: (src << 3) | rel  (src < 2^16) ----
__global__ __launch_bounds__(256) void place_kernel(const int* __restrict__ src,
                                                    const int* __restrict__ dst,
                                                    const int* __restrict__ et,
                                                    int* __restrict__ cursor,
                                                    u32* __restrict__ epk, int E) {
    int e = blockIdx.x * 256 + threadIdx.x;
    if (e < E) {
        int r = et[e];
        int key = dst[e] * R + r;
        int p = atomicAdd(&cursor[key], 1);
        epk[p] = ((u32)src[e] << 3) | (u32)r;
    }
}

// ---- pack both layers' B into MFMA B-frag order; also zero cnt_i ----
// layout: [layer][ct(9)][kc(4)][g(8)][lane(64)][j(8)]
__global__ __launch_bounds__(256) void bprep2_kernel(const float* __restrict__ w1,
                                                     const float* __restrict__ root1,
                                                     u16* __restrict__ Bf1,
                                                     const float* __restrict__ w2,
                                                     const float* __restrict__ root2,
                                                     u16* __restrict__ Bf2,
                                                     int4* __restrict__ cntz) {
    int gidx = blockIdx.x * 256 + threadIdx.x;  // over 2*9*4*8*64 = 36864
    // fused: zero cnt_i (NR ints = NR/4 int4)
    for (int i = gidx; i < NR / 4; i += 36864)
        cntz[i] = make_int4(0, 0, 0, 0);
    if (gidx >= 2 * 9 * 4 * 8 * 64) return;
    const int layer = gidx / (9 * 4 * 8 * 64);
    const int idx = gidx - layer * (9 * 4 * 8 * 64);
    const float* w = layer ? w2 : w1;
    const float* root = layer ? root2 : root1;
    u16* Bfrag = layer ? Bf2 : Bf1;
    const int lane = idx & 63;
    const int g = (idx >> 6) & 7;
    const int kc = (idx >> 9) & 3;
    const int ct = idx >> 11;  // 0..8
    const int col = ct * 128 + g * 16 + (lane & 15);
    const int kbase = kc * 32 + (lane >> 4) * 8;
    u16* o = Bfrag + (size_t)idx * 8;
#pragma unroll
    for (int j = 0; j < 8; ++j) {
        const int k = kbase + j;
        float v = (col < R * D) ? w[(size_t)(col >> 7) * (D * D) + (size_t)k * D + (col & 127)]
                                : root[(size_t)k * D + (col - R * D)];
        o[j] = f2bf(v);
    }
}

// ---- GEMM: y[n,:] = xin[n,:] @ [W_1..W_8, root]  (K=128, bf16 out) ----
// grid 782; ct-loop inside so xin is read once. B slice (32 KB) staged per ct
// with immediate load->ds_write inside the barrier pair (no regs live across
// a barrier -> no spill; see round-10 post-mortem). INF32: read fp32 x
// directly, convert in-register (replaces the xcast kernel).
template <bool INF32>
__global__ __launch_bounds__(256, 4) void gemm_xw(const void* __restrict__ xin,
                                                  const u16* __restrict__ Bfrag,
                                                  u16* __restrict__ y) {
    __shared__ uint4 Bs[2048];  // 32 KB

    const int t = threadIdx.x;
    const int wave = t >> 6;
    const int lane = t & 63;
    const int quad = lane >> 4;
    const int l15 = lane & 15;
    const int n0 = blockIdx.x * 64;
    const int n = n0 + wave * 16 + l15;
    const int nc = (n < NN) ? n : (NN - 1);

    // A fragments (K = 128 -> 4 chunks), loaded once
    bf16x8 a0, a1, a2, a3;
    if (INF32) {
        const float* xr = (const float*)xin + (size_t)nc * D + quad * 8;
#pragma unroll
        for (int c = 0; c < 4; ++c) {
            float4 v0 = *(const float4*)(xr + c * 32);
            float4 v1 = *(const float4*)(xr + c * 32 + 4);
            bf16x8 a;
            a[0] = (short)f2bf(v0.x); a[1] = (short)f2bf(v0.y);
            a[2] = (short)f2bf(v0.z); a[3] = (short)f2bf(v0.w);
            a[4] = (short)f2bf(v1.x); a[5] = (short)f2bf(v1.y);
            a[6] = (short)f2bf(v1.z); a[7] = (short)f2bf(v1.w);
            if (c == 0) a0 = a; else if (c == 1) a1 = a;
            else if (c == 2) a2 = a; else a3 = a;
        }
    } else {
        const u16* xr = (const u16*)xin + (size_t)nc * D + quad * 8;
        a0 = *(const bf16x8*)(xr);
        a1 = *(const bf16x8*)(xr + 32);
        a2 = *(const bf16x8*)(xr + 64);
        a3 = *(const bf16x8*)(xr + 96);
    }

#pragma unroll 1
    for (int ct = 0; ct < 9; ++ct) {
        const uint4* bsrc = (const uint4*)Bfrag + (size_t)ct * 2048 + t;

        __syncthreads();  // previous tile's LDS reads complete
#pragma unroll
        for (int i = 0; i < 8; ++i) Bs[t + 256 * i] = bsrc[256 * i];
        __syncthreads();  // stage visible

        f32x4 acc[8];
#pragma unroll
        for (int g = 0; g < 8; ++g) acc[g] = (f32x4){0.f, 0.f, 0.f, 0.f};

        const u16* bb = (const u16*)Bs + lane * 8;
#pragma unroll
        for (int g = 0; g < 8; ++g) {
            bf16x8 b0 = *(const bf16x8*)(bb + (0 * 8 + g) * 512);
            acc[g] = __builtin_amdgcn_mfma_f32_16x16x32_bf16(a0, b0, acc[g], 0, 0, 0);
            bf16x8 b1 = *(const bf16x8*)(bb + (1 * 8 + g) * 512);
            acc[g] = __builtin_amdgcn_mfma_f32_16x16x32_bf16(a1, b1, acc[g], 0, 0, 0);
            bf16x8 b2 = *(const bf16x8*)(bb + (2 * 8 + g) * 512);
            acc[g] = __builtin_amdgcn_mfma_f32_16x16x32_bf16(a2, b2, acc[g], 0, 0, 0);
            bf16x8 b3 = *(const bf16x8*)(bb + (3 * 8 + g) * 512);
            acc[g] = __builtin_amdgcn_mfma_f32_16x16x32_bf16(a3, b3, acc[g], 0, 0, 0);
        }

        // epilogue: D mapping row = quad*4 + q, col = g*16 + l15
#pragma unroll
        for (int g = 0; g < 8; ++g) {
            const int col = ct * 128 + g * 16 + l15;
#pragma unroll
            for (int q = 0; q < 4; ++q) {
                const int row = n0 + wave * 16 + quad * 4 + q;
                if (row < NN)
                    y[(size_t)row * KO + col] = f2bf(acc[g][q]);
            }
        }
    }
}

// ---- aggregate: out[n] = relu( sum_e scale*y[src_e, r_e*128..] + y[n,1024..] + b )
// One wave per node; per-edge packed (src<<3|r) -> yoff/scale recovered per
// 64-edge chunk (scale from cnt_i[n*8+r], one coalesced 32 B region per wave);
// 4-wide batched gathers for MLP.
template <bool OUTBF>
__global__ __launch_bounds__(256) void agg_kernel(const u32* __restrict__ yv,
                                                  const int* __restrict__ off,
                                                  const u32* __restrict__ epk,
                                                  const int* __restrict__ cnt,
                                                  const float* __restrict__ bias,
                                                  void* __restrict__ outp) {
    const int n = blockIdx.x * 4 + (threadIdx.x >> 6);
    const int lane = threadIdx.x & 63;
    const int e0 = off[n * 8], e1 = off[n * 8 + 8];

    float ax = 0.f, ay = 0.f;
    int cbase = e0;
    u32 yoff = 0u; float sc = 0.f;
    if (cbase + lane < e1) {
        const u32 pk = epk[cbase + lane];
        const int r = (int)(pk & 7u);
        yoff = (pk >> 3) * (KO / 2) + (u32)r * (D / 2);
        sc = 1.0f / (float)cnt[n * 8 + r];
    }

    int i = e0;
    while (i < e1) {
        const int chunk_end = (e1 < cbase + 64) ? e1 : (cbase + 64);
        for (; i + 3 < chunk_end; i += 4) {
            const int j = i - cbase;
            const u32 p0 = (u32)__shfl((int)yoff, j);
            const u32 p1 = (u32)__shfl((int)yoff, j + 1);
            const u32 p2 = (u32)__shfl((int)yoff, j + 2);
            const u32 p3 = (u32)__shfl((int)yoff, j + 3);
            const float f0 = __shfl(sc, j);
            const float f1 = __shfl(sc, j + 1);
            const float f2 = __shfl(sc, j + 2);
            const float f3 = __shfl(sc, j + 3);
            const u32 v0 = yv[(size_t)p0 + lane];
            const u32 v1 = yv[(size_t)p1 + lane];
            const u32 v2 = yv[(size_t)p2 + lane];
            const u32 v3 = yv[(size_t)p3 + lane];
            ax += f0 * bf2f((u16)(v0 & 0xFFFFu)); ay += f0 * bf2f((u16)(v0 >> 16));
            ax += f1 * bf2f((u16)(v1 & 0xFFFFu)); ay += f1 * bf2f((u16)(v1 >> 16));
            ax += f2 * bf2f((u16)(v2 & 0xFFFFu)); ay += f2 * bf2f((u16)(v2 >> 16));
            ax += f3 * bf2f((u16)(v3 & 0xFFFFu)); ay += f3 * bf2f((u16)(v3 >> 16));
        }
        for (; i < chunk_end; ++i) {
            const int j = i - cbase;
            const u32 p0 = (u32)__shfl((int)yoff, j);
            const float f0 = __shfl(sc, j);
            const u32 v0 = yv[(size_t)p0 + lane];
            ax += f0 * bf2f((u16)(v0 & 0xFFFFu));
            ay += f0 * bf2f((u16)(v0 >> 16));
        }
        if (i < e1) {  // next chunk of 64 edges (rare)
            cbase += 64;
            if (cbase + lane < e1) {
                const u32 pk = epk[cbase + lane];
                const int r = (int)(pk & 7u);
                yoff = (pk >> 3) * (KO / 2) + (u32)r * (D / 2);
                sc = 1.0f / (float)cnt[n * 8 + r];
            } else { yoff = 0u; sc = 0.f; }
        }
    }

    // root term + bias + relu
    const u32 rv = yv[(size_t)n * (KO / 2) + (R * D / 2) + lane];
    const float2 bb = ((const float2*)bias)[lane];
    const float ox = fmaxf(ax + bf2f((u16)(rv & 0xFFFFu)) + bb.x, 0.f);
    const float oy = fmaxf(ay + bf2f((u16)(rv >> 16)) + bb.y, 0.f);
    if (OUTBF)
        ((u32*)outp)[(size_t)n * 64 + lane] = (u32)f2bf(ox) | ((u32)f2bf(oy) << 16);
    else
        ((float2*)outp)[(size_t)n * 64 + lane] = make_float2(ox, oy);
}

extern "C" void kernel_launch(void* const* d_in, const int* in_sizes, int n_in,
                              void* d_out, int out_size, void* d_ws, size_t ws_size,
                              hipStream_t stream) {
    const float* x = (const float*)d_in[0];
    const int* ei = (const int*)d_in[1];
    const int* et = (const int*)d_in[2];
    const float* w1 = (const float*)d_in[3];
    const float* root1 = (const float*)d_in[4];
    const float* b1 = (const float*)d_in[5];
    const float* w2 = (const float*)d_in[6];
    const float* root2 = (const float*)d_in[7];
    const float* b2 = (const float*)d_in[8];
    float* out = (float*)d_out;

    char* ws = (char*)d_ws;
    int* off    = (int*)(ws + 0);                  // (NR+1) ints
    int* cnt_i  = (int*)(ws + 1600512);            // NR ints (kept live for agg)
    int* cursor = (int*)(ws + 3200512);            // NR ints
    int* bsum   = (int*)(ws + 4800512);            // NSB ints
    u32* epk    = (u32*)(ws + 4804096);            // EE u32 (2.4 MB)
    u32* h      = (u32*)(ws + 7204096);            // N*D bf16 = 12.8 MB
    u16* y      = (u16*)(ws + 20004096);           // N*1152 bf16 = 115.2 MB
    u16* Bf1    = (u16*)(ws + 135204096);          // 294912 B
    u16* Bf2    = (u16*)(ws + 135499008);          // 294912 B

    const int* srcp = ei;
    const int* dstp = ei + EE;

    // ---- weight pack + cnt zero (one kernel), then CSR build ----
    bprep2_kernel<<<144, 256, 0, stream>>>(w1, root1, Bf1, w2, root2, Bf2,
                                           (int4*)cnt_i);
    hist_kernel<<<(EE + 255) / 256, 256, 0, stream>>>(dstp, et, cnt_i, EE);
    scanA<<<NSB, 256, 0, stream>>>(cnt_i, off, bsum);
    scanBC<<<NSB, 256, 0, stream>>>(off, cursor, bsum);
    place_kernel<<<(EE + 255) / 256, 256, 0, stream>>>(srcp, dstp, et, cursor,
                                                       epk, EE);

    const int gemm_blocks = (NN + 63) / 64;   // 782
    const int agg_blocks = NN / 4;            // 12500

    // layer 1: x (fp32) -> y -> h (bf16)
    gemm_xw<true><<<gemm_blocks, 256, 0, stream>>>(x, Bf1, y);
    agg_kernel<true><<<agg_blocks, 256, 0, stream>>>((const u32*)y, off, epk,
                                                     cnt_i, b1, h);

    // layer 2: h -> y -> out (fp32)
    gemm_xw<false><<<gemm_blocks, 256, 0, stream>>>(h, Bf2, y);
    agg_kernel<false><<<agg_blocks, 256, 0, stream>>>((const u32*)y, off, epk,
                                                      cnt_i, b2, out);
}